// Round 13
// baseline (242.064 us; speedup 1.0000x reference)
//
#include <hip/hip_runtime.h>

typedef __bf16 bf16;
typedef bf16  bf16x8 __attribute__((ext_vector_type(8)));
typedef bf16  bf16x4 __attribute__((ext_vector_type(4)));
typedef short s16x4  __attribute__((ext_vector_type(4)));
typedef float f32x4  __attribute__((ext_vector_type(4)));

#define AS1 __attribute__((address_space(1)))
#define AS3 __attribute__((address_space(3)))

#define SQLEN 2048
#define EMB   1024

// ---------------- fused fp32 -> bf16 convert: x + 4 weights, ONE dispatch ----
__global__ __launch_bounds__(256) void cvt_all(const float* __restrict__ x,
                                               const float* __restrict__ w0, const float* __restrict__ w1,
                                               const float* __restrict__ w2, const float* __restrict__ w3,
                                               bf16* __restrict__ xo,
                                               bf16* o0, bf16* o1, bf16* o2, bf16* o3) {
  const int NX = 1024 * 1024;   // 8M / 8
  const int NW = 131072;        // 1M / 8
  const int i = blockIdx.x * blockDim.x + threadIdx.x;  // grid = 6144*256 exactly
  const float* in; bf16* out; int idx;
  if (i < NX) { in = x; out = xo; idx = i; }
  else {
    const int j = i - NX;
    const int w = j >> 17;      // NW = 2^17
    idx = j & (NW - 1);
    switch (w) {
      case 0: in = w0; out = o0; break;
      case 1: in = w1; out = o1; break;
      case 2: in = w2; out = o2; break;
      default: in = w3; out = o3; break;
    }
  }
  const float4* p = (const float4*)in + (size_t)idx * 2;
  float4 a = p[0], b = p[1];
  bf16x8 o;
  o[0] = (bf16)a.x; o[1] = (bf16)a.y; o[2] = (bf16)a.z; o[3] = (bf16)a.w;
  o[4] = (bf16)b.x; o[5] = (bf16)b.y; o[6] = (bf16)b.z; o[7] = (bf16)b.w;
  *((bf16x8*)out + idx) = o;
}

// ---------------- fused QKV GEMM: one block computes Q,K,V 128x128 tiles ----
// R17: grid swapped to (8,64): blockIdx.x = n-tile, blockIdx.y = m-tile.
// linear_id % 8 == n-tile -> each XCD serves ONE n-tile; its 0.75MB B panel
// (Wq+Wk+Wv 128 cols) stays L2-resident for the whole dispatch (old layout:
// every XCD touched all 8 n-tiles = 6MB > 4MB L2). A-tile reuse -> L3.
__global__ __launch_bounds__(256, 2)
void gemm_qkv(const bf16* __restrict__ A, const bf16* __restrict__ Wq,
              const bf16* __restrict__ Wk, const bf16* __restrict__ Wv,
              bf16* __restrict__ Qo, bf16* __restrict__ Ko, bf16* __restrict__ Vto,
              float qscale) {
  __shared__ bf16 Asl[2 * 4096];
  __shared__ bf16 Bsl[3][2 * 4096];

  const int tid  = threadIdx.x;
  const int lane = tid & 63, wave = tid >> 6;
  const int quad = lane >> 4, col = lane & 15;
  const int m0 = blockIdx.y * 128, n0 = blockIdx.x * 128;   // swapped
  const int wr = wave >> 1, wc = wave & 1;
  const int K = 1024, N = 1024;

  const bf16* const Bp[3] = {Wq, Wk, Wv};

  f32x4 acc[3][4][4];
  const f32x4 fz = {0.f, 0.f, 0.f, 0.f};
#pragma unroll
  for (int s = 0; s < 3; ++s)
#pragma unroll
    for (int i = 0; i < 4; ++i)
#pragma unroll
      for (int j = 0; j < 4; ++j) acc[s][i][j] = fz;

  const int srow = lane >> 2;
  const int sk   = lane & 3;

  auto stage = [&](int buf, int k0) {
#pragma unroll
    for (int r = 0; r < 2; ++r) {
      const int c      = wave * 2 + r;
      const int row    = c * 16 + srow;
      const int gchunk = sk ^ (row & 3);
      const bf16* ga = A + (size_t)(m0 + row) * K + k0 + gchunk * 8;
      __builtin_amdgcn_global_load_lds((const AS1 void*)ga,
          (AS3 void*)(Asl + buf * 4096 + c * 512), 16, 0, 0);
#pragma unroll
      for (int s = 0; s < 3; ++s) {
        const bf16* gb = Bp[s] + (size_t)(n0 + row) * K + k0 + gchunk * 8;
        __builtin_amdgcn_global_load_lds((const AS1 void*)gb,
            (AS3 void*)(&Bsl[s][buf * 4096 + c * 512]), 16, 0, 0);
      }
    }
  };

  const int nk = K >> 5;   // 32
  stage(0, 0);
  for (int it = 0; it < nk; ++it) {
    __syncthreads();
    if (it + 1 < nk) stage((it + 1) & 1, (it + 1) << 5);
    const bf16* As = Asl + (it & 1) * 4096;

    bf16x8 af[4];
#pragma unroll
    for (int i = 0; i < 4; ++i) {
      const int r = wr * 64 + i * 16 + col;
      af[i] = *(const bf16x8*)&As[r * 32 + ((quad ^ (col & 3)) * 8)];
    }
#pragma unroll
    for (int s = 0; s < 3; ++s) {
      const bf16* Bs = &Bsl[s][(it & 1) * 4096];
      bf16x8 bfr[4];
#pragma unroll
      for (int j = 0; j < 4; ++j) {
        const int r = wc * 64 + j * 16 + col;
        bfr[j] = *(const bf16x8*)&Bs[r * 32 + ((quad ^ (col & 3)) * 8)];
      }
#pragma unroll
      for (int i = 0; i < 4; ++i)
#pragma unroll
        for (int j = 0; j < 4; ++j)
          acc[s][i][j] = __builtin_amdgcn_mfma_f32_16x16x32_bf16(af[i], bfr[j], acc[s][i][j], 0, 0, 0);
    }
  }

  // ---- epilogue: Q (scaled), K plain, V transposed ----
#pragma unroll
  for (int s = 0; s < 3; ++s) {
    const float sc = (s == 0) ? qscale : 1.0f;
#pragma unroll
    for (int i = 0; i < 4; ++i) {
#pragma unroll
      for (int j = 0; j < 4; ++j) {
        const int gm0 = m0 + wr * 64 + i * 16 + quad * 4;
        const int gn  = n0 + wc * 64 + j * 16 + col;
        if (s == 2) {
          bf16x4 ob;
#pragma unroll
          for (int r = 0; r < 4; ++r) ob[r] = (bf16)(acc[s][i][j][r]);
          const int bb = gm0 >> 11;        // m = bb*2048 + t
          const int t_ = gm0 & 2047;
          *(bf16x4*)&Vto[((size_t)(bb * 1024 + gn)) * 2048 + t_] = ob;
        } else {
          bf16* C = (s == 0) ? Qo : Ko;
#pragma unroll
          for (int r = 0; r < 4; ++r)
            C[(size_t)(gm0 + r) * N + gn] = (bf16)(acc[s][i][j][r] * sc);
        }
      }
    }
  }
}

// ---------------- output GEMM: C[8192,1024] = Y * Wo^T, f32 out ----
// R16 ring (2 K-chunks/barrier) + R17 grid swap (x = n-tile -> Wo panel
// 0.25MB L2-pinned per XCD).
__global__ __launch_bounds__(256, 2)
void gemm_o(const bf16* __restrict__ A, const bf16* __restrict__ W, float* __restrict__ Cf) {
  __shared__ bf16 Asl[4 * 4096];   // 32KB: slots 0..3 (chunk & 3)
  __shared__ bf16 Bsl[4 * 4096];   // 32KB

  const int tid  = threadIdx.x;
  const int lane = tid & 63, wave = tid >> 6;
  const int quad = lane >> 4, col = lane & 15;
  const int m0 = blockIdx.y * 128, n0 = blockIdx.x * 128;   // swapped
  const int wr = wave >> 1, wc = wave & 1;
  const int K = 1024, N = 1024;

  f32x4 acc[4][4];
  const f32x4 fz = {0.f, 0.f, 0.f, 0.f};
#pragma unroll
  for (int i = 0; i < 4; ++i)
#pragma unroll
    for (int j = 0; j < 4; ++j) acc[i][j] = fz;

  const int srow = lane >> 2;
  const int sk   = lane & 3;

  auto stage = [&](int slot, int k0) {
#pragma unroll
    for (int r = 0; r < 2; ++r) {
      const int c      = wave * 2 + r;
      const int row    = c * 16 + srow;
      const int gchunk = sk ^ (row & 3);
      const bf16* ga = A + (size_t)(m0 + row) * K + k0 + gchunk * 8;
      const bf16* gb = W + (size_t)(n0 + row) * K + k0 + gchunk * 8;
      __builtin_amdgcn_global_load_lds((const AS1 void*)ga, (AS3 void*)(Asl + slot * 4096 + c * 512), 16, 0, 0);
      __builtin_amdgcn_global_load_lds((const AS1 void*)gb, (AS3 void*)(Bsl + slot * 4096 + c * 512), 16, 0, 0);
    }
  };

  stage(0, 0);
  stage(1, 32);
  for (int pp = 0; pp < 16; ++pp) {          // 16 barrier-iters, 2 chunks each
    __syncthreads();
    if (pp + 1 < 16) {
      stage((2 * pp + 2) & 3, (2 * pp + 2) * 32);
      stage((2 * pp + 3) & 3, (2 * pp + 3) * 32);
    }
#pragma unroll
    for (int h = 0; h < 2; ++h) {
      const int ck = 2 * pp + h;
      const bf16* As = Asl + (ck & 3) * 4096;
      const bf16* Bs = Bsl + (ck & 3) * 4096;

      bf16x8 af[4], bfr[4];
#pragma unroll
      for (int i = 0; i < 4; ++i) {
        const int r = wr * 64 + i * 16 + col;
        af[i] = *(const bf16x8*)&As[r * 32 + ((quad ^ (col & 3)) * 8)];
      }
#pragma unroll
      for (int j = 0; j < 4; ++j) {
        const int r = wc * 64 + j * 16 + col;
        bfr[j] = *(const bf16x8*)&Bs[r * 32 + ((quad ^ (col & 3)) * 8)];
      }
#pragma unroll
      for (int i = 0; i < 4; ++i)
#pragma unroll
        for (int j = 0; j < 4; ++j)
          acc[i][j] = __builtin_amdgcn_mfma_f32_16x16x32_bf16(af[i], bfr[j], acc[i][j], 0, 0, 0);
    }
  }

#pragma unroll
  for (int i = 0; i < 4; ++i) {
#pragma unroll
    for (int j = 0; j < 4; ++j) {
      const int gm0 = m0 + wr * 64 + i * 16 + quad * 4;
      const int gn  = n0 + wc * 64 + j * 16 + col;
#pragma unroll
      for (int r = 0; r < 4; ++r)
        Cf[(size_t)(gm0 + r) * N + gn] = acc[i][j][r];
    }
  }
}

// ---------------- flash causal attention, S^T, 8 waves x 1 q-strip ----------------
// R17: exact revert to the R13 variant (best-measured: 73.0-73.2 us across
// replays; VGPR 64). The 4-wave/2-strip (R14) and pipelined (R15) variants
// measured equal-or-worse within the +/-8us run-to-run noise band.
// Q pre-scaled by 0.125*log2(e). Vt: [(b*1024+n), t].
// KVBLK=128 (17 paired iters), l via ones-MFMA, XCD-grouped block decode,
// T13 defer-rescale, T5 setprio, direct-to-global epilogue, R7 pairing.
__global__ __launch_bounds__(512, 4)
void attn_flash(const bf16* __restrict__ Q, const bf16* __restrict__ K,
                const bf16* __restrict__ Vt, bf16* __restrict__ Y) {
  __shared__ bf16 Ksb0[2 * 8192];   // [buf][128 keys][64 d]   32KB
  __shared__ bf16 Vsb0[2 * 8192];   // [buf][64 d][128 t]      32KB

  const int tid  = threadIdx.x;
  const int lane = tid & 63, wave = tid >> 6;   // wave 0..7
  const int quad = lane >> 4, col = lane & 15;

  // XCD-grouped decode: XCD g = bid&7 handles bh in [g*8, g*8+8)
  const int B_ = blockIdx.x;            // 0..511
  const int bh = (B_ & 7) * 8 + (B_ >> 6);
  const int p  = (B_ >> 3) & 7;         // pair index 0..7
  const int h  = bh & 15;
  const int b  = bh >> 4;
  const int hc = h * 64;
  const size_t rowBase = (size_t)b * SQLEN;

  const int srow8 = lane >> 3;
  const int sch   = lane & 7;
  const int a7    = col & 7;

  auto stageKV = [&](int buf, int t0) {
#pragma unroll
    for (int i = 0; i < 2; ++i) {
      const int krow = wave * 16 + i * 8 + srow8;          // krow&7 == srow8
      const int kch  = sch ^ srow8;
      const bf16* gk = K + (rowBase + t0 + krow) * EMB + hc + kch * 8;
      __builtin_amdgcn_global_load_lds((const AS1 void*)gk,
          (AS3 void*)(Ksb0 + buf * 8192 + wave * 1024 + i * 512), 16, 0, 0);
      const int vrow = wave * 8 + i * 4 + (lane >> 4);
      const int vch  = (lane & 15) ^ (vrow & 7);
      const bf16* gv = Vt + ((size_t)(b * EMB + hc + vrow)) * SQLEN + t0 + vch * 8;
      __builtin_amdgcn_global_load_lds((const AS1 void*)gv,
          (AS3 void*)(Vsb0 + buf * 8192 + wave * 1024 + i * 512), 16, 0, 0);
    }
  };

  const s16x4 ones = {(short)0x3F80, (short)0x3F80, (short)0x3F80, (short)0x3F80};

  for (int halfIdx = 0; halfIdx < 2; ++halfIdx) {
    const int qt = halfIdx == 0 ? (15 - p) : p;  // paired: ntt sums to 17
    const int q0 = qt * 128;
    const int ntt = qt + 1;                      // 128-key tiles

    stageKV(0, 0);

    bf16x8 qf0, qf1;
    {
      const int row = wave * 16 + col;
      const bf16* gq = Q + (rowBase + q0 + row) * EMB + hc + quad * 8;
      qf0 = *(const bf16x8*)gq;
      qf1 = *(const bf16x8*)(gq + 32);
    }
    __syncthreads();   // K/V tile 0 staged

    float m_i = -INFINITY;
    f32x4 o[4], ol;
    const f32x4 fz = {0.f, 0.f, 0.f, 0.f};
#pragma unroll
    for (int dd = 0; dd < 4; ++dd) o[dd] = fz;
    ol = fz;

    for (int tt = 0; tt < ntt; ++tt) {
      const int t0 = tt * 128;
      const int cur = tt & 1;
      if (tt + 1 < ntt) stageKV(cur ^ 1, t0 + 128);  // prefetch in flight
      const bf16* Ks = Ksb0 + cur * 8192;
      const bf16* Vs = Vsb0 + cur * 8192;

      // ---- S^T: 8 slabs of 16 keys ----
      f32x4 s[8];
      __builtin_amdgcn_s_setprio(1);
#pragma unroll
      for (int sl = 0; sl < 8; ++sl) {
        const bf16x8 kf0 = *(const bf16x8*)&Ks[(sl * 16 + col) * 64 + ((quad ^ a7) * 8)];
        const bf16x8 kf1 = *(const bf16x8*)&Ks[(sl * 16 + col) * 64 + (((quad ^ 4) ^ a7) * 8)];
        f32x4 z = fz;
        z = __builtin_amdgcn_mfma_f32_16x16x32_bf16(kf0, qf0, z, 0, 0, 0);
        s[sl] = __builtin_amdgcn_mfma_f32_16x16x32_bf16(kf1, qf1, z, 0, 0, 0);
      }
      __builtin_amdgcn_s_setprio(0);

      if (tt == qt) {  // single diagonal tile: global-index causal mask
        const int qg = q0 + wave * 16 + col;
#pragma unroll
        for (int sl = 0; sl < 8; ++sl)
#pragma unroll
          for (int r = 0; r < 4; ++r)
            if (t0 + sl * 16 + quad * 4 + r > qg) s[sl][r] = -INFINITY;
      }

      // ---- online softmax (T13 defer-rescale); l via ones-MFMA below ----
      bf16x4 pb[8];
      {
        float mx = s[0][0];
#pragma unroll
        for (int sl = 0; sl < 8; ++sl)
#pragma unroll
          for (int r = 0; r < 4; ++r) mx = fmaxf(mx, s[sl][r]);
        mx = fmaxf(mx, __shfl_xor(mx, 16));
        mx = fmaxf(mx, __shfl_xor(mx, 32));
        if (!__all(mx <= m_i + 8.f)) {   // rescale only on real max growth
          const float mnew = fmaxf(m_i, mx);
          const float a = __builtin_amdgcn_exp2f(m_i - mnew);
#pragma unroll
          for (int dd = 0; dd < 4; ++dd) o[dd] *= a;
          ol *= a;
          m_i = mnew;
        }
#pragma unroll
        for (int sl = 0; sl < 8; ++sl)
#pragma unroll
          for (int r = 0; r < 4; ++r)
            pb[sl][r] = (bf16)__builtin_amdgcn_exp2f(s[sl][r] - m_i);  // <= 2^8
      }

      // ---- O^T += V^T P^T; l += 1^T P^T (ones-MFMA) ----
      __builtin_amdgcn_s_setprio(1);
#pragma unroll
      for (int sl = 0; sl < 8; ++sl) {
        const s16x4 pf = __builtin_bit_cast(s16x4, pb[sl]);
        ol = __builtin_amdgcn_mfma_f32_16x16x16bf16_1k(ones, pf, ol, 0, 0, 0);
        const int cch  = 2 * sl + (quad >> 1);   // 0..15
        const int half = quad & 1;
#pragma unroll
        for (int dd = 0; dd < 4; ++dd) {
          const int row = dd * 16 + col;
          const bf16x4 vb = *(const bf16x4*)&Vs[row * 128 + ((cch ^ a7) * 8) + half * 4];
          const s16x4 vf = __builtin_bit_cast(s16x4, vb);
          o[dd] = __builtin_amdgcn_mfma_f32_16x16x16bf16_1k(vf, pf, o[dd], 0, 0, 0);
        }
      }
      __builtin_amdgcn_s_setprio(0);
      __syncthreads();  // drains prefetch; guards dbuf reuse
    }

    // ---- epilogue: O^T/l straight to global (l replicated in every ol lane) ----
    {
      const float rl = __builtin_amdgcn_rcpf(ol[0]);
      const size_t yrow = (rowBase + q0 + wave * 16 + col) * EMB + hc;
#pragma unroll
      for (int dd = 0; dd < 4; ++dd) {
        bf16x4 ob;
#pragma unroll
        for (int r = 0; r < 4; ++r) ob[r] = (bf16)(o[dd][r] * rl);
        *(bf16x4*)&Y[yrow + dd * 16 + quad * 4] = ob;
      }
    }
  }
}

// ---------------- launcher ----------------
extern "C" void kernel_launch(void* const* d_in, const int* in_sizes, int n_in,
                              void* d_out, int out_size, void* d_ws, size_t ws_size,
                              hipStream_t stream) {
  const float* x  = (const float*)d_in[0];
  const float* Wq = (const float*)d_in[1];
  const float* Wk = (const float*)d_in[2];
  const float* Wv = (const float*)d_in[3];
  const float* Wo = (const float*)d_in[4];
  float* out = (float*)d_out;

  const size_t ME = 8192ull * 1024ull;
  const size_t WE = 1024ull * 1024ull;
  bf16* ws  = (bf16*)d_ws;
  bf16* xb  = ws;
  bf16* wqb = xb + ME;
  bf16* wkb = wqb + WE;
  bf16* wvb = wkb + WE;
  bf16* wob = wvb + WE;
  bf16* Qb  = wob + WE;
  bf16* Kb  = Qb + ME;
  bf16* Vtb = Kb + ME;   // V written directly transposed by gemm_qkv
  bf16* Yb  = Vtb + ME;

  // one convert dispatch: 6144 blocks cover x (4096) + 4 weights (2048)
  cvt_all<<<6144, 256, 0, stream>>>(x, Wq, Wk, Wv, Wo, xb, wqb, wkb, wvb, wob);

  const float qscale = 0.125f * 1.4426950408889634f;
  gemm_qkv<<<dim3(8, 64), 256, 0, stream>>>(xb, wqb, wkb, wvb, Qb, Kb, Vtb, qscale);

  attn_flash<<<512, 512, 0, stream>>>(Qb, Kb, Vtb, Yb);

  gemm_o<<<dim3(8, 64), 256, 0, stream>>>(Yb, wob, out);
}